// Round 2
// 128.693 us; speedup vs baseline: 1.0998x; 1.0998x over previous
//
#include <hip/hip_runtime.h>
#include <hip/hip_bf16.h>

typedef unsigned short u16;
typedef __attribute__((ext_vector_type(8))) short bf16x8;   // 8 bf16 = 4 VGPRs
typedef __attribute__((ext_vector_type(4))) short bf16x4;
typedef __attribute__((ext_vector_type(4))) float f32x4;

#define NBG   5000
#define NPID  5532
#define NTOT  15532      // 5000 + 5532 + 5000
#define FEAT  256
#define BATCH 4096
#define SCALE_LOG2E 43.280851226668994f   // 30 * log2(e)
#define LPITCH 264       // f32-fallback LDS pitch (shorts)

#define NTILE_B  976             // 61 chunks x 16 tiles; 971 real, 5 zero-pad
#define TILE_SH  4096            // shorts per 16-col tile (16*256)
#define NTILE_A  256             // 4096 rows / 16
#define STEP_SH  8192            // shorts per 32-col step (2 tiles)

// ---- workspace layout (bytes) ----
#define TABT_BYTES ((size_t)NTILE_B * TILE_SH * 2)   // 7,995,392
#define AT_BYTES   ((size_t)NTILE_A * TILE_SH * 2)   // 2,097,152
#define SUMS_OFF   (TABT_BYTES + AT_BYTES)
// S floats: [0,4096) bg | [4096,8192) nb | 8192 det | 8193 oim | 8194 nv | 8195 ticket
#define SUMS_FLOATS 8196
#define WS_NEED    (SUMS_OFF + SUMS_FLOATS * 4)

// raw v_exp_f32: args are in [-43.3, 43.3] -> no denorm/overflow fixups needed
__device__ __forceinline__ float fexp2(float x) {
#if __has_builtin(__builtin_amdgcn_exp2f)
    return __builtin_amdgcn_exp2f(x);
#else
    return exp2f(x);
#endif
}

__device__ __forceinline__ void atomic_add_f(float* p, float v) {
    __hip_atomic_fetch_add(p, v, __ATOMIC_RELAXED, __HIP_MEMORY_SCOPE_AGENT);
}
__device__ __forceinline__ short f2bf(float f) {
    return (short)__bfloat16_as_ushort(__float2bfloat16(f));
}
// bank-conflict swizzle: q-slot XORed with row/col bits 1..2.
// ds_read_b128 at l15*64 + q*16 bytes was 8-way conflicted per 16-lane phase;
// with q^=(rc>>1)&3 it is 2-way (free, m136).
__device__ __forceinline__ int swz(int rc, int q) { return q ^ ((rc >> 1) & 3); }

__device__ __forceinline__ const float* table_row(
    int n, const float* __restrict__ lut, const float* __restrict__ cq,
    const float* __restrict__ cqb)
{
    const int nc = n < NTOT ? n : NTOT - 1;
    if (nc < NBG)        return cqb + (size_t)nc * FEAT;
    if (nc < NBG + NPID) return lut + (size_t)(nc - NBG) * FEAT;
    return cq + (size_t)(nc - NBG - NPID) * FEAT;
}

// -------- Stage 0: f32 -> bf16 tiled prepass (table + inputs) + zero sums --
// Tile format (8192 B per 16-col tile): short off = kk*512 + col*32 + swz(col,q)*8
// holding src[col][kk*32 + q*8 .. +8]. Table rows are PRE-SCALED by 30*log2e
// so the score kernel's exp argument is the raw MFMA accumulator (no mul).
#define TAB_UNITS (NTILE_B * 512)    // 499,712
#define A_UNITS   (NTILE_A * 512)    // 131,072
#define PRE_BLOCKS ((TAB_UNITS + A_UNITS) / 256)   // 2464

__global__ __launch_bounds__(256) void prepass_kernel(
    const float* __restrict__ inputs, const float* __restrict__ lut,
    const float* __restrict__ cq, const float* __restrict__ cqb,
    u16* __restrict__ tabt, u16* __restrict__ at, float* __restrict__ S)
{
    const int u = blockIdx.x * 256 + threadIdx.x;
    if (u < SUMS_FLOATS) S[u] = 0.f;

    if (u < TAB_UNITS) {
        const int tile = u >> 9, v = u & 511;
        const int kk = v >> 6, col = (v >> 2) & 15, q = v & 3;
        const int cg = tile * 16 + col;
        bf16x8 r = {0, 0, 0, 0, 0, 0, 0, 0};
        if (cg < NTOT) {
            const float* src = table_row(cg, lut, cq, cqb) + kk * 32 + q * 8;
            const f32x4 lo = *(const f32x4*)src;
            const f32x4 hi = *(const f32x4*)(src + 4);
            r = bf16x8{ f2bf(lo[0] * SCALE_LOG2E), f2bf(lo[1] * SCALE_LOG2E),
                        f2bf(lo[2] * SCALE_LOG2E), f2bf(lo[3] * SCALE_LOG2E),
                        f2bf(hi[0] * SCALE_LOG2E), f2bf(hi[1] * SCALE_LOG2E),
                        f2bf(hi[2] * SCALE_LOG2E), f2bf(hi[3] * SCALE_LOG2E) };
        }
        const size_t off = (size_t)tile * TILE_SH + kk * 512 + col * 32 + swz(col, q) * 8;
        *(bf16x8*)(tabt + off) = r;
    } else {
        const int ua = u - TAB_UNITS;
        const int tile = ua >> 9, v = ua & 511;
        const int kk = v >> 6, row = (v >> 2) & 15, q = v & 3;
        const float* src = inputs + (size_t)(tile * 16 + row) * FEAT + kk * 32 + q * 8;
        const f32x4 lo = *(const f32x4*)src;
        const f32x4 hi = *(const f32x4*)(src + 4);
        bf16x8 r = { f2bf(lo[0]), f2bf(lo[1]), f2bf(lo[2]), f2bf(lo[3]),
                     f2bf(hi[0]), f2bf(hi[1]), f2bf(hi[2]), f2bf(hi[3]) };
        const size_t off = (size_t)tile * TILE_SH + kk * 512 + row * 32 + swz(row, q) * 8;
        *(bf16x8*)(at + off) = r;
    }
}

// -------- Stage 1: fused GEMM + exp-sum, LDS-shared B ----------------------
// 976 blocks (16 rowchunks x 61 colchunks), XCD-swizzled. 4 waves; wave owns
// 4 row-tiles (64 rows) in register A-frags (sweet spot: each B ds_read feeds
// 4 MFMAs). 32-col steps (two 16-col tiles, 16 KB) double-buffered in LDS,
// ONE barrier/step: write(t) targets the buffer last read at consume(t-2),
// which completed before barrier(t-1) -> no hazard. Tail chunk (60) runs 6
// steps over tiles 960..971 with per-column masking (pad tiles give
// exp2(0)=1 which the mask kills).
__global__ __launch_bounds__(256, 2) void score_bf16_kernel(
    const u16* __restrict__ tabt, const u16* __restrict__ at,
    float* __restrict__ sum_bg, float* __restrict__ sum_nb)
{
    __shared__ __align__(16) short lbuf[2][STEP_SH];
    const int lid = blockIdx.x;
    const int x8  = lid & 7;
    const int j   = lid >> 3;                 // [0, 122)
    const int rowchunk = x8 * 2 + (j & 1);    // [0, 16)
    const int colchunk = j >> 1;              // [0, 61)

    const int tid  = threadIdx.x;
    const int wave = tid >> 6;
    const int lane = tid & 63;
    const int l15  = lane & 15;
    const int quad = lane >> 4;
    const int frag_off = l15 * 32 + swz(l15, quad) * 8;  // shorts within kk-block

    // A fragments: 4 row-tiles, coalesced 1 KB/wave reads (swizzled format).
    bf16x8 af[4][8];
    {
        const u16* ab = at + (size_t)(rowchunk * 16 + wave * 4) * TILE_SH + frag_off;
        #pragma unroll
        for (int s = 0; s < 4; ++s)
            #pragma unroll
            for (int kk = 0; kk < 8; ++kk)
                af[s][kk] = *(const bf16x8*)(ab + (size_t)s * TILE_SH + kk * 512);
    }

    float pbg[16], pnb[16];
    #pragma unroll
    for (int i = 0; i < 16; ++i) { pbg[i] = 0.f; pnb[i] = 0.f; }

    const int steps = (colchunk == 60) ? 6 : 8;
    const u16* gbase = tabt + (size_t)colchunk * 16 * TILE_SH;

    // preload step-0 staging regs (each thread 64 B, four contiguous 4 KB quarters)
    bf16x8 r0, r1, r2, r3;
    {
        r0 = *(const bf16x8*)(gbase + tid * 8);
        r1 = *(const bf16x8*)(gbase + 2048 + tid * 8);
        r2 = *(const bf16x8*)(gbase + 4096 + tid * 8);
        r3 = *(const bf16x8*)(gbase + 6144 + tid * 8);
    }

    #pragma unroll 1
    for (int t = 0; t < steps; ++t) {
        {
            short* dst = lbuf[t & 1];
            *(bf16x8*)(dst + tid * 8)        = r0;
            *(bf16x8*)(dst + 2048 + tid * 8) = r1;
            *(bf16x8*)(dst + 4096 + tid * 8) = r2;
            *(bf16x8*)(dst + 6144 + tid * 8) = r3;
        }
        if (t + 1 < steps) {                   // prefetch next step into regs
            const u16* g = gbase + (size_t)(t + 1) * STEP_SH;
            r0 = *(const bf16x8*)(g + tid * 8);
            r1 = *(const bf16x8*)(g + 2048 + tid * 8);
            r2 = *(const bf16x8*)(g + 4096 + tid * 8);
            r3 = *(const bf16x8*)(g + 6144 + tid * 8);
        }
        __syncthreads();                       // step t visible to all waves

        const short* lb = lbuf[t & 1];
        #pragma unroll
        for (int h = 0; h < 2; ++h) {
            const int bt = colchunk * 16 + t * 2 + h;   // global 16-col tile idx
            f32x4 cc[4];
            #pragma unroll
            for (int s = 0; s < 4; ++s) cc[s] = f32x4{0.f, 0.f, 0.f, 0.f};
            #pragma unroll
            for (int kk = 0; kk < 8; ++kk) {
                const bf16x8 b = *(const bf16x8*)(lb + h * TILE_SH + kk * 512 + frag_off);
                cc[0] = __builtin_amdgcn_mfma_f32_16x16x32_bf16(af[0][kk], b, cc[0], 0, 0, 0);
                cc[1] = __builtin_amdgcn_mfma_f32_16x16x32_bf16(af[1][kk], b, cc[1], 0, 0, 0);
                cc[2] = __builtin_amdgcn_mfma_f32_16x16x32_bf16(af[2][kk], b, cc[2], 0, 0, 0);
                cc[3] = __builtin_amdgcn_mfma_f32_16x16x32_bf16(af[3][kk], b, cc[3], 0, 0, 0);
            }

            if (colchunk == 60) {              // tail: mask pad cols (incl tile 971)
                const bool okc = (bt * 16 + l15) < NTOT;
                #pragma unroll
                for (int s = 0; s < 4; ++s)
                    #pragma unroll
                    for (int r = 0; r < 4; ++r)
                        pnb[s * 4 + r] += okc ? fexp2(cc[s][r]) : 0.f;
            } else if (bt < 312) {             // all background
                #pragma unroll
                for (int s = 0; s < 4; ++s)
                    #pragma unroll
                    for (int r = 0; r < 4; ++r)
                        pbg[s * 4 + r] += fexp2(cc[s][r]);
            } else if (bt > 312) {             // all non-bg
                #pragma unroll
                for (int s = 0; s < 4; ++s)
                    #pragma unroll
                    for (int r = 0; r < 4; ++r)
                        pnb[s * 4 + r] += fexp2(cc[s][r]);
            } else {                           // tile 312: cols 4992..5007
                const bool isbg = l15 < 8;
                #pragma unroll
                for (int s = 0; s < 4; ++s)
                    #pragma unroll
                    for (int r = 0; r < 4; ++r) {
                        const float e = fexp2(cc[s][r]);
                        pbg[s * 4 + r] += isbg ? e : 0.f;
                        pnb[s * 4 + r] += isbg ? 0.f : e;
                    }
            }
        }
    }

    #pragma unroll
    for (int off = 1; off < 16; off <<= 1) {
        #pragma unroll
        for (int i = 0; i < 16; ++i) {
            pbg[i] += __shfl_xor(pbg[i], off);
            pnb[i] += __shfl_xor(pnb[i], off);
        }
    }
    if (l15 == 0) {
        #pragma unroll
        for (int s = 0; s < 4; ++s) {
            #pragma unroll
            for (int r = 0; r < 4; ++r) {
                const int row = (rowchunk * 16 + wave * 4 + s) * 16 + quad * 4 + r;
                atomic_add_f(&sum_bg[row], pbg[s * 4 + r]);
                atomic_add_f(&sum_nb[row], pnb[s * 4 + r]);
            }
        }
    }
}

// -------- Stage 1 (f32 fallback, round-4 structure, proven) ----------------
__global__ __launch_bounds__(256, 2) void score_f32_kernel(
    const float* __restrict__ inputs, const float* __restrict__ lut,
    const float* __restrict__ cq, const float* __restrict__ cqb,
    float* __restrict__ sum_bg, float* __restrict__ sum_nb)
{
    __shared__ __align__(16) short lds[32 * LPITCH];
    const int wave = threadIdx.x >> 6;
    const int lane = threadIdx.x & 63;
    const int l15  = lane & 15;
    const int quad = lane >> 4;
    const int rowbase = blockIdx.y * 256;
    const int colbase = blockIdx.x * 256;

    bf16x8 afrag[4][8];
    #pragma unroll 1
    for (int c = 0; c < 8; ++c) {
        __syncthreads();
        #pragma unroll
        for (int i = 0; i < 8; ++i) {
            const int lr = i * 4 + wave;
            const f32x4 v = *(const f32x4*)(inputs + (size_t)(rowbase + c * 32 + lr) * FEAT + lane * 4);
            bf16x4 h = { f2bf(v[0]), f2bf(v[1]), f2bf(v[2]), f2bf(v[3]) };
            *(bf16x4*)(&lds[lr * LPITCH + lane * 4]) = h;
        }
        __syncthreads();
        if ((c >> 1) == wave) {
            const int half = c & 1;
            #pragma unroll
            for (int j2 = 0; j2 < 2; ++j2) {
                const int lr = j2 * 16 + l15;
                #pragma unroll
                for (int kk = 0; kk < 8; ++kk)
                    afrag[half * 2 + j2][kk] =
                        *(const bf16x8*)(&lds[lr * LPITCH + kk * 32 + quad * 8]);
            }
        }
    }

    float pbg[16], pnb[16];
    #pragma unroll
    for (int i = 0; i < 16; ++i) { pbg[i] = 0.f; pnb[i] = 0.f; }

    #pragma unroll 1
    for (int s = 0; s < 8; ++s) {
        __syncthreads();
        #pragma unroll
        for (int i = 0; i < 8; ++i) {
            const int lc = i * 4 + wave;
            const f32x4 v = *(const f32x4*)(table_row(colbase + s * 32 + lc, lut, cq, cqb) + lane * 4);
            bf16x4 h = { f2bf(v[0]), f2bf(v[1]), f2bf(v[2]), f2bf(v[3]) };
            *(bf16x4*)(&lds[lc * LPITCH + lane * 4]) = h;
        }
        __syncthreads();

        #pragma unroll
        for (int st = 0; st < 2; ++st) {
            const int lc = st * 16 + l15;
            f32x4 cc[4];
            #pragma unroll
            for (int q = 0; q < 4; ++q) cc[q] = f32x4{0.f, 0.f, 0.f, 0.f};
            #pragma unroll
            for (int kk = 0; kk < 8; ++kk) {
                const bf16x8 b = *(const bf16x8*)(&lds[lc * LPITCH + kk * 32 + quad * 8]);
                cc[0] = __builtin_amdgcn_mfma_f32_16x16x32_bf16(afrag[0][kk], b, cc[0], 0, 0, 0);
                cc[1] = __builtin_amdgcn_mfma_f32_16x16x32_bf16(afrag[1][kk], b, cc[1], 0, 0, 0);
                cc[2] = __builtin_amdgcn_mfma_f32_16x16x32_bf16(afrag[2][kk], b, cc[2], 0, 0, 0);
                cc[3] = __builtin_amdgcn_mfma_f32_16x16x32_bf16(afrag[3][kk], b, cc[3], 0, 0, 0);
            }
            const int n = colbase + s * 32 + st * 16 + l15;
            const bool okc  = n < NTOT;
            const bool isbg = n < NBG;
            #pragma unroll
            for (int q = 0; q < 4; ++q) {
                #pragma unroll
                for (int r = 0; r < 4; ++r) {
                    float e = exp2f(cc[q][r] * SCALE_LOG2E);
                    e = okc ? e : 0.f;
                    pbg[q * 4 + r] += isbg ? e : 0.f;
                    pnb[q * 4 + r] += isbg ? 0.f : e;
                }
            }
        }
    }

    #pragma unroll
    for (int off = 1; off < 16; off <<= 1) {
        #pragma unroll
        for (int i = 0; i < 16; ++i) {
            pbg[i] += __shfl_xor(pbg[i], off);
            pnb[i] += __shfl_xor(pnb[i], off);
        }
    }
    if (l15 == 0) {
        #pragma unroll
        for (int q = 0; q < 4; ++q) {
            #pragma unroll
            for (int r = 0; r < 4; ++r) {
                const int row = rowbase + wave * 64 + q * 16 + quad * 4 + r;
                atomic_add_f(&sum_bg[row], pbg[q * 4 + r]);
                atomic_add_f(&sum_nb[row], pnb[q * 4 + r]);
            }
        }
    }
}

// -------- Stage 2: finalize (128 blocks; wave = 8 rows) + scalar fold ------
__global__ __launch_bounds__(256) void finalize_kernel(
    const float* __restrict__ inputs, const int* __restrict__ roi_label,
    const float* __restrict__ lut,
    const float* __restrict__ sum_bg, const float* __restrict__ sum_nb,
    float* __restrict__ accums, unsigned int* __restrict__ ticket,
    float* __restrict__ out)
{
    __shared__ float s_det[4], s_oim[4], s_nv[4];
    const int wid  = threadIdx.x >> 6;
    const int lane = threadIdx.x & 63;

    float det_a = 0.f, oim_a = 0.f, nv_a = 0.f;

    #pragma unroll 1
    for (int it = 0; it < 8; ++it) {
        const int row = blockIdx.x * 32 + wid * 8 + it;
        const int r   = roi_label[row];

        float dot = 0.f;
        {
            const int rc = r < 0 ? 0 : r;
            const f32x4 xi = *(const f32x4*)(inputs + (size_t)row * FEAT + lane * 4);
            const f32x4 li = *(const f32x4*)(lut + (size_t)rc * FEAT + lane * 4);
            #pragma unroll
            for (int jj = 0; jj < 4; ++jj) {
                float a = __bfloat162float(__float2bfloat16(xi[jj]));
                float b = __bfloat162float(__float2bfloat16(li[jj]));
                dot += a * b;
            }
        }
        #pragma unroll
        for (int off = 32; off > 0; off >>= 1) dot += __shfl_xor(dot, off);

        if (lane == 0) {
            const float sbg = sum_bg[row];
            const float snb = sum_nb[row];
            const float inv = 1.f / (sbg + snb);
            const float cls0 = sbg * inv;
            const float cls1 = snb * inv;
            out[2 * row]     = cls0;
            out[2 * row + 1] = cls1;

            const float cs = (r >= -1) ? cls1 : cls0;
            const float om = 1.f - cs;
            det_a += -(0.25f * om * om * logf(cs)) * (1.f / (float)BATCH);
            nv_a  += (r >= -1) ? 1.f : 0.f;

            if (r >= 0) {
                const float slab = 30.f * dot;
                const float logp = slab - logf(snb);
                const float p    = expf(logp);
                const float om2  = 1.f - p;
                oim_a += -(0.25f * om2 * om2 * logp) * cls1 * cls1;
            }
        }
    }

    if (lane == 0) { s_det[wid] = det_a; s_oim[wid] = oim_a; s_nv[wid] = nv_a; }
    __syncthreads();
    if (threadIdx.x == 0) {
        atomic_add_f(&accums[0], s_det[0] + s_det[1] + s_det[2] + s_det[3]);
        atomic_add_f(&accums[1], s_oim[0] + s_oim[1] + s_oim[2] + s_oim[3]);
        atomic_add_f(&accums[2], s_nv[0] + s_nv[1] + s_nv[2] + s_nv[3]);
        __threadfence();
        const unsigned t = __hip_atomic_fetch_add(ticket, 1u, __ATOMIC_ACQ_REL,
                                                  __HIP_MEMORY_SCOPE_AGENT);
        if (t == gridDim.x - 1) {
            const float det = __hip_atomic_load(&accums[0], __ATOMIC_RELAXED, __HIP_MEMORY_SCOPE_AGENT);
            const float oim = __hip_atomic_load(&accums[1], __ATOMIC_RELAXED, __HIP_MEMORY_SCOPE_AGENT);
            float nv        = __hip_atomic_load(&accums[2], __ATOMIC_RELAXED, __HIP_MEMORY_SCOPE_AGENT);
            if (nv < 1.f) nv = 1.f;
            out[2 * BATCH]     = det;
            out[2 * BATCH + 1] = oim / nv;
        }
    }
}

extern "C" void kernel_launch(void* const* d_in, const int* in_sizes, int n_in,
                              void* d_out, int out_size, void* d_ws, size_t ws_size,
                              hipStream_t stream)
{
    const float* inputs = (const float*)d_in[0];
    const int*   roi    = (const int*)d_in[1];
    const float* lut    = (const float*)d_in[2];
    const float* cq     = (const float*)d_in[3];
    const float* cqb    = (const float*)d_in[4];
    float* out = (float*)d_out;

    if (ws_size >= (size_t)WS_NEED) {
        u16* tabt = (u16*)d_ws;
        u16* at   = (u16*)((char*)d_ws + TABT_BYTES);
        float* S  = (float*)((char*)d_ws + SUMS_OFF);
        prepass_kernel<<<PRE_BLOCKS, 256, 0, stream>>>(inputs, lut, cq, cqb, tabt, at, S);
        score_bf16_kernel<<<976, 256, 0, stream>>>(tabt, at, S, S + BATCH);
        finalize_kernel<<<128, 256, 0, stream>>>(
            inputs, roi, lut, S, S + BATCH, S + 2 * BATCH,
            (unsigned int*)(S + 2 * BATCH + 3), out);
    } else {
        float* S = (float*)d_ws;
        hipMemsetAsync(S, 0, SUMS_FLOATS * sizeof(float), stream);
        dim3 g1(61, 16);
        score_f32_kernel<<<g1, 256, 0, stream>>>(inputs, lut, cq, cqb, S, S + BATCH);
        finalize_kernel<<<128, 256, 0, stream>>>(
            inputs, roi, lut, S, S + BATCH, S + 2 * BATCH,
            (unsigned int*)(S + 2 * BATCH + 3), out);
    }
}